// Round 1
// baseline (608.147 us; speedup 1.0000x reference)
//
#include <hip/hip_runtime.h>
#include <hip/hip_bf16.h>

typedef __bf16 bf16_t;
typedef bf16_t bf16x8 __attribute__((ext_vector_type(8)));
typedef bf16_t bf16x4 __attribute__((ext_vector_type(4)));
typedef float f32x4 __attribute__((ext_vector_type(4)));

// ---- workspace layout (bytes) ----
// 0      : wq  bf16 [256][256]   (131072 B)
// 131072 : wkv bf16 [512][256]   (262144 B)
// 393216 : wo  bf16 [256][256]   (131072 B)
// 524288 : bias8 f32 [8][64][64] (131072 B)
#define WS_WKV_OFF 65536   // elems
#define WS_WO_OFF  196608  // elems
#define WS_B8_OFF  524288  // bytes

__global__ __launch_bounds__(256) void prep_kernel(
    const float* __restrict__ wq, const float* __restrict__ wkv,
    const float* __restrict__ wo, const float* __restrict__ bt,
    const int* __restrict__ rp,
    bf16_t* __restrict__ wsq, bf16_t* __restrict__ wskv,
    bf16_t* __restrict__ wso, float* __restrict__ bias8) {
  int t = blockIdx.x * 256 + threadIdx.x;
  if (t < 65536)  wsq[t]  = (bf16_t)wq[t];
  if (t < 131072) wskv[t] = (bf16_t)wkv[t];
  if (t < 65536)  wso[t]  = (bf16_t)wo[t];
  if (t < 4096) {
    int idx = rp[t];
#pragma unroll
    for (int h = 0; h < 8; ++h) bias8[h * 4096 + t] = bt[idx * 8 + h];
  }
}

// LDS map (bf16 elems):
//   xs  [64][264] @ 0            (33792 B)  -- overlaid by O [64][264] after phase 2
//   per-wave region @ 16896 + wid*7424:
//     Q  [64][40]  (+0,   2560 el)   \ overlaid by P [64][72] (4608 el)
//     K  [64][40]  (+2560, 2560 el)  /   after S is computed
//     Vt [32][72]  (+5120, 2304 el)
// total 76288 elems = 152576 B dynamic LDS
#define LDS_TOTAL_BYTES 152576

__global__ __launch_bounds__(512, 2) void win_attn_kernel(
    const float* __restrict__ x, const float* __restrict__ mask,
    const float* __restrict__ bq, const float* __restrict__ bkv,
    const float* __restrict__ bo,
    const bf16_t* __restrict__ wsq, const bf16_t* __restrict__ wskv,
    const bf16_t* __restrict__ wso, const float* __restrict__ bias8,
    float* __restrict__ out) {
  extern __shared__ bf16_t lds[];
  const int b    = blockIdx.x;
  const int tid  = threadIdx.x;
  const int wid  = tid >> 6;
  const int lane = tid & 63;
  const int lrow = lane & 15;
  const int lgrp = lane >> 4;

  // ---------- phase 1: stage x (f32) -> bf16 LDS xs[64][264] ----------
  {
    const float4* xv = (const float4*)(x + (size_t)b * 16384);
#pragma unroll
    for (int j = 0; j < 8; ++j) {
      int i4 = j * 512 + tid;
      float4 v = xv[i4];
      int e = i4 * 4;
      int r = e >> 8, c = e & 255;
      bf16x4 w = {(bf16_t)v.x, (bf16_t)v.y, (bf16_t)v.z, (bf16_t)v.w};
      *(bf16x4*)(lds + r * 264 + c) = w;
    }
  }
  __syncthreads();

  const int h = wid;
  bf16_t* ldsQ  = lds + 16896 + wid * 7424;
  bf16_t* ldsK  = ldsQ + 2560;
  bf16_t* ldsVt = ldsQ + 5120;
  bf16_t* ldsP  = ldsQ;   // overlays Q,K after S
  bf16_t* ldsO  = lds;    // overlays xs after phase 2

  // ---------- phase 2: per-head QKV projection (bf16 MFMA) ----------
  const bf16_t* WQh = wsq  + h * 32 * 256;
  const bf16_t* WKh = wskv + h * 32 * 256;
  const bf16_t* WVh = wskv + (256 + h * 32) * 256;
  f32x4 aq[4][2], ak[4][2], av[4][2];
  const f32x4 zf = {0.f, 0.f, 0.f, 0.f};
#pragma unroll
  for (int tm = 0; tm < 4; ++tm)
#pragma unroll
    for (int tn = 0; tn < 2; ++tn) { aq[tm][tn] = zf; ak[tm][tn] = zf; av[tm][tn] = zf; }

#pragma unroll
  for (int ks = 0; ks < 8; ++ks) {
    bf16x8 af[4];
#pragma unroll
    for (int tm = 0; tm < 4; ++tm)
      af[tm] = *(const bf16x8*)(lds + (tm * 16 + lrow) * 264 + ks * 32 + lgrp * 8);
    bf16x8 bqf[2], bkf[2], bvf[2];
#pragma unroll
    for (int tn = 0; tn < 2; ++tn) {
      int wr = (tn * 16 + lrow) * 256 + ks * 32 + lgrp * 8;
      bqf[tn] = *(const bf16x8*)(WQh + wr);
      bkf[tn] = *(const bf16x8*)(WKh + wr);
      bvf[tn] = *(const bf16x8*)(WVh + wr);
    }
#pragma unroll
    for (int tm = 0; tm < 4; ++tm)
#pragma unroll
      for (int tn = 0; tn < 2; ++tn) {
        aq[tm][tn] = __builtin_amdgcn_mfma_f32_16x16x32_bf16(af[tm], bqf[tn], aq[tm][tn], 0, 0, 0);
        ak[tm][tn] = __builtin_amdgcn_mfma_f32_16x16x32_bf16(af[tm], bkf[tn], ak[tm][tn], 0, 0, 0);
        av[tm][tn] = __builtin_amdgcn_mfma_f32_16x16x32_bf16(af[tm], bvf[tn], av[tm][tn], 0, 0, 0);
      }
  }

  // epilogue: bias, scale Q, write bf16 Q/K row-major, V transposed
  const float scale = 0.17677669529663687f;  // 1/sqrt(32)
#pragma unroll
  for (int tn = 0; tn < 2; ++tn) {
    float bqv = bq[h * 32 + tn * 16 + lrow];
    float bkv_ = bkv[h * 32 + tn * 16 + lrow];
    float bvv = bkv[256 + h * 32 + tn * 16 + lrow];
#pragma unroll
    for (int tm = 0; tm < 4; ++tm) {
#pragma unroll
      for (int r = 0; r < 4; ++r) {
        int row = tm * 16 + lgrp * 4 + r;
        ldsQ[row * 40 + tn * 16 + lrow] = (bf16_t)((aq[tm][tn][r] + bqv) * scale);
        ldsK[row * 40 + tn * 16 + lrow] = (bf16_t)(ak[tm][tn][r] + bkv_);
      }
      bf16x4 vv;
#pragma unroll
      for (int r = 0; r < 4; ++r) vv[r] = (bf16_t)(av[tm][tn][r] + bvv);
      *(bf16x4*)(ldsVt + (tn * 16 + lrow) * 72 + tm * 16 + lgrp * 4) = vv;
    }
  }
  __syncthreads();  // all xs reads done; O may overlay xs later

  // ---------- phase 3: S = Q K^T (+bias+mask), softmax (wave-private) ----------
  f32x4 s[4][4];
  {
    bf16x8 qf[4], kf[4];
#pragma unroll
    for (int t = 0; t < 4; ++t) {
      qf[t] = *(const bf16x8*)(ldsQ + (t * 16 + lrow) * 40 + lgrp * 8);
      kf[t] = *(const bf16x8*)(ldsK + (t * 16 + lrow) * 40 + lgrp * 8);
    }
#pragma unroll
    for (int tm = 0; tm < 4; ++tm)
#pragma unroll
      for (int tc = 0; tc < 4; ++tc)
        s[tm][tc] = __builtin_amdgcn_mfma_f32_16x16x32_bf16(qf[tm], kf[tc], zf, 0, 0, 0);
  }
  const float* maskw = mask + (size_t)(b & 1023) * 4096;
  const float* biash = bias8 + h * 4096;
  float rs[4][4];
#pragma unroll
  for (int tm = 0; tm < 4; ++tm) {
    float val[4][4];
    float mx[4] = {-1e30f, -1e30f, -1e30f, -1e30f};
#pragma unroll
    for (int tc = 0; tc < 4; ++tc)
#pragma unroll
      for (int r = 0; r < 4; ++r) {
        int row = tm * 16 + lgrp * 4 + r, col = tc * 16 + lrow;
        float v = s[tm][tc][r] + biash[row * 64 + col] + maskw[row * 64 + col];
        val[tc][r] = v;
        mx[r] = fmaxf(mx[r], v);
      }
#pragma unroll
    for (int r = 0; r < 4; ++r) {
      float m = mx[r];
      m = fmaxf(m, __shfl_xor(m, 1));
      m = fmaxf(m, __shfl_xor(m, 2));
      m = fmaxf(m, __shfl_xor(m, 4));
      m = fmaxf(m, __shfl_xor(m, 8));
      mx[r] = m;
    }
    float sm[4] = {0.f, 0.f, 0.f, 0.f};
#pragma unroll
    for (int tc = 0; tc < 4; ++tc)
#pragma unroll
      for (int r = 0; r < 4; ++r) {
        float p = __expf(val[tc][r] - mx[r]);
        val[tc][r] = p;
        sm[r] += p;
      }
#pragma unroll
    for (int r = 0; r < 4; ++r) {
      float t = sm[r];
      t += __shfl_xor(t, 1);
      t += __shfl_xor(t, 2);
      t += __shfl_xor(t, 4);
      t += __shfl_xor(t, 8);
      rs[tm][r] = 1.0f / t;  // deferred normalization
    }
#pragma unroll
    for (int tc = 0; tc < 4; ++tc)
#pragma unroll
      for (int r = 0; r < 4; ++r)
        ldsP[(tm * 16 + lgrp * 4 + r) * 72 + tc * 16 + lrow] = (bf16_t)val[tc][r];
  }

  // ---------- phase 4: O_h = P V (wave-private), normalize in epilogue ----------
  f32x4 o[4][2];
#pragma unroll
  for (int tm = 0; tm < 4; ++tm)
#pragma unroll
    for (int tn = 0; tn < 2; ++tn) o[tm][tn] = zf;
#pragma unroll
  for (int ks = 0; ks < 2; ++ks) {
    bf16x8 pf[4], vf[2];
#pragma unroll
    for (int tm = 0; tm < 4; ++tm)
      pf[tm] = *(const bf16x8*)(ldsP + (tm * 16 + lrow) * 72 + ks * 32 + lgrp * 8);
#pragma unroll
    for (int tn = 0; tn < 2; ++tn)
      vf[tn] = *(const bf16x8*)(ldsVt + (tn * 16 + lrow) * 72 + ks * 32 + lgrp * 8);
#pragma unroll
    for (int tm = 0; tm < 4; ++tm)
#pragma unroll
      for (int tn = 0; tn < 2; ++tn)
        o[tm][tn] = __builtin_amdgcn_mfma_f32_16x16x32_bf16(pf[tm], vf[tn], o[tm][tn], 0, 0, 0);
  }
#pragma unroll
  for (int tm = 0; tm < 4; ++tm)
#pragma unroll
    for (int tn = 0; tn < 2; ++tn)
#pragma unroll
      for (int r = 0; r < 4; ++r)
        ldsO[(tm * 16 + lgrp * 4 + r) * 264 + h * 32 + tn * 16 + lrow] =
            (bf16_t)(o[tm][tn][r] * rs[tm][r]);
  __syncthreads();

  // ---------- phase 5: out = O @ w_o^T + b_o ----------
  const int nb = wid * 32;
  f32x4 oc[4][2];
#pragma unroll
  for (int tm = 0; tm < 4; ++tm)
#pragma unroll
    for (int tn = 0; tn < 2; ++tn) oc[tm][tn] = zf;
#pragma unroll
  for (int ks = 0; ks < 8; ++ks) {
    bf16x8 af[4], bf_[2];
#pragma unroll
    for (int tm = 0; tm < 4; ++tm)
      af[tm] = *(const bf16x8*)(ldsO + (tm * 16 + lrow) * 264 + ks * 32 + lgrp * 8);
#pragma unroll
    for (int tn = 0; tn < 2; ++tn)
      bf_[tn] = *(const bf16x8*)(wso + (nb + tn * 16 + lrow) * 256 + ks * 32 + lgrp * 8);
#pragma unroll
    for (int tm = 0; tm < 4; ++tm)
#pragma unroll
      for (int tn = 0; tn < 2; ++tn)
        oc[tm][tn] = __builtin_amdgcn_mfma_f32_16x16x32_bf16(af[tm], bf_[tn], oc[tm][tn], 0, 0, 0);
  }
  float* outw = out + (size_t)b * 16384;
#pragma unroll
  for (int tn = 0; tn < 2; ++tn) {
    float bov = bo[nb + tn * 16 + lrow];
#pragma unroll
    for (int tm = 0; tm < 4; ++tm)
#pragma unroll
      for (int r = 0; r < 4; ++r)
        outw[(tm * 16 + lgrp * 4 + r) * 256 + nb + tn * 16 + lrow] = oc[tm][tn][r] + bov;
  }
}

extern "C" void kernel_launch(void* const* d_in, const int* in_sizes, int n_in,
                              void* d_out, int out_size, void* d_ws, size_t ws_size,
                              hipStream_t stream) {
  const float* x    = (const float*)d_in[0];
  const float* mask = (const float*)d_in[1];
  const float* wq   = (const float*)d_in[2];
  const float* bq   = (const float*)d_in[3];
  const float* wkv  = (const float*)d_in[4];
  const float* bkv  = (const float*)d_in[5];
  const float* bt   = (const float*)d_in[6];
  const float* wo   = (const float*)d_in[7];
  const float* bo   = (const float*)d_in[8];
  const int*   rp   = (const int*)d_in[9];
  float* out = (float*)d_out;

  bf16_t* wsq  = (bf16_t*)d_ws;
  bf16_t* wskv = wsq + WS_WKV_OFF;
  bf16_t* wso  = wsq + WS_WO_OFF;
  float*  bias8 = (float*)((char*)d_ws + WS_B8_OFF);

  prep_kernel<<<512, 256, 0, stream>>>(wq, wkv, wo, bt, rp, wsq, wskv, wso, bias8);

  (void)hipFuncSetAttribute((const void*)win_attn_kernel,
                            hipFuncAttributeMaxDynamicSharedMemorySize, LDS_TOTAL_BYTES);
  win_attn_kernel<<<4096, 512, LDS_TOTAL_BYTES, stream>>>(
      x, mask, bq, bkv, bo, wsq, wskv, wso, bias8, out);
}